// Round 5
// baseline (248.932 us; speedup 1.0000x reference)
//
#include <hip/hip_runtime.h>
#include <math.h>
#include <stdint.h>

typedef _Float16 half8v __attribute__((ext_vector_type(8)));
typedef _Float16 half4v __attribute__((ext_vector_type(4)));
typedef _Float16 half2v __attribute__((ext_vector_type(2)));
typedef __fp16 fp16x2 __attribute__((ext_vector_type(2)));
typedef float floatx4 __attribute__((ext_vector_type(4)));

#define MFMA16(a, b, c) __builtin_amdgcn_mfma_f32_16x16x32_f16(a, b, c, 0, 0, 0)

// Q pre-scale: 1/sqrt(64) * log2(e), folded so attention uses exp2 directly.
#define QSCALE 0.18033688011112f

// Async global->LDS, 16B per lane. LDS dest must be wave-uniform base + lane*16;
// the GLOBAL source address is per-lane arbitrary (it's a gather).
__device__ __forceinline__ void gld_lds16(const void* g, void* l) {
  __builtin_amdgcn_global_load_lds(
      (const __attribute__((address_space(1))) uint32_t*)(uintptr_t)g,
      (__attribute__((address_space(3))) uint32_t*)(uintptr_t)l, 16, 0, 0);
}

// Packed f32x2 -> f16x2 (rtz), bit-cast to our _Float16 vector type.
__device__ __forceinline__ half2v pk16(float a, float b) {
  fp16x2 t = __builtin_amdgcn_cvt_pkrtz(a, b);
  return __builtin_bit_cast(half2v, t);
}

// LDS bank swizzle for 64-col fp16 tiles (128B rows), 16B blocks.
__device__ __forceinline__ int swz(int row, int blk) {
  return row * 64 + ((blk ^ (row & 7)) << 3);
}

// LDS bank swizzle for 32-col fp16 tiles (64B rows = 16 banks): XOR chunk
// with (row>>1)&3 so 16-row b128 frag reads are 2-way, not 8-way.
__device__ __forceinline__ int vswz(int row, int blk) {
  return row * 32 + ((blk ^ ((row >> 1) & 3)) << 3);
}

// GEMM 32-col tile swizzle (same math as vswz; kept separate for clarity).
__device__ __forceinline__ int gswz(int row, int blk) {
  return row * 32 + ((blk ^ ((row >> 1) & 3)) << 3);
}

// ---------------------------------------------------------------------------
// Prep (fused): blocks 0..2047 convert X fp32->fp16; blocks 2048..3071
// transpose+convert the weights.  (unchanged)
// ---------------------------------------------------------------------------
__global__ __launch_bounds__(256) void prep(
    const float* __restrict__ X, const float* __restrict__ Wq,
    const float* __restrict__ Wkv, const float* __restrict__ Wo,
    _Float16* __restrict__ X16, _Float16* __restrict__ WqkvT,
    _Float16* __restrict__ WoT)
{
  __shared__ alignas(16) _Float16 Tt[64 * 68];
  const int bid = blockIdx.x;
  if (bid < 2048) {
    size_t gid = (size_t)bid * 256 + threadIdx.x;
    const float4* src = (const float4*)(X) + gid * 2;
    float4 a = src[0], b = src[1];
    half8v h;
    h[0]=(_Float16)a.x; h[1]=(_Float16)a.y; h[2]=(_Float16)a.z; h[3]=(_Float16)a.w;
    h[4]=(_Float16)b.x; h[5]=(_Float16)b.y; h[6]=(_Float16)b.z; h[7]=(_Float16)b.w;
    *((half8v*)X16 + gid) = h;
    return;
  }
  int b = bid - 2048;
  const float* src; _Float16* dst; int N, tk, tn;
  if (b < 256)      { src = Wq;  dst = WqkvT;                 N = 1024; tk = b & 15;        tn = b >> 4; }
  else if (b < 768) { src = Wkv; dst = WqkvT + (size_t)1024 * 1024; N = 2048; tk = (b - 256) & 15; tn = (b - 256) >> 4; }
  else              { src = Wo;  dst = WoT;                   N = 1024; tk = (b - 768) & 15; tn = (b - 768) >> 4; }

  const int t = threadIdx.x;
  {
    int kg = t >> 4, ng = t & 15;
    const float* sp = src + (size_t)(tk * 64 + kg * 4) * N + tn * 64 + ng * 4;
    float4 r0 = *(const float4*)(sp);
    float4 r1 = *(const float4*)(sp + N);
    float4 r2 = *(const float4*)(sp + 2 * N);
    float4 r3 = *(const float4*)(sp + 3 * N);
    half4v h;
    h[0]=(_Float16)r0.x; h[1]=(_Float16)r1.x; h[2]=(_Float16)r2.x; h[3]=(_Float16)r3.x;
    *(half4v*)&Tt[(ng * 4 + 0) * 68 + kg * 4] = h;
    h[0]=(_Float16)r0.y; h[1]=(_Float16)r1.y; h[2]=(_Float16)r2.y; h[3]=(_Float16)r3.y;
    *(half4v*)&Tt[(ng * 4 + 1) * 68 + kg * 4] = h;
    h[0]=(_Float16)r0.z; h[1]=(_Float16)r1.z; h[2]=(_Float16)r2.z; h[3]=(_Float16)r3.z;
    *(half4v*)&Tt[(ng * 4 + 2) * 68 + kg * 4] = h;
    h[0]=(_Float16)r0.w; h[1]=(_Float16)r1.w; h[2]=(_Float16)r2.w; h[3]=(_Float16)r3.w;
    *(half4v*)&Tt[(ng * 4 + 3) * 68 + kg * 4] = h;
  }
  __syncthreads();
  #pragma unroll
  for (int i = 0; i < 2; i++) {
    int idx = t + i * 256;
    int nl = idx >> 3, k8 = (idx & 7) * 8;
    half8v v = *(half8v*)&Tt[nl * 68 + k8];
    *(half8v*)(dst + (size_t)(tn * 64 + nl) * 1024 + tk * 64 + k8) = v;
  }
}

// ---------------------------------------------------------------------------
// Kernel 1: QKV projection (unchanged: m97 structure + gswz).
// ---------------------------------------------------------------------------
__global__ __launch_bounds__(256) void qkv_gemm(
    const _Float16* __restrict__ X16, const _Float16* __restrict__ WqkvT,
    _Float16* __restrict__ q_ws, _Float16* __restrict__ k_ws,
    _Float16* __restrict__ vT_ws)
{
  constexpr int K = 1024;
  __shared__ alignas(16) _Float16 Tt[128 * 136];
  _Float16* As = Tt;
  _Float16* Bs = Tt + 4096;

  const int m0 = blockIdx.x * 128;
  const int n0 = blockIdx.y * 128;

  const int tid  = threadIdx.x;
  const int wave = tid >> 6, lane = tid & 63;
  const int qd = lane >> 4, l15 = lane & 15;
  const int wr = (wave >> 1) * 64, wc = (wave & 1) * 64;
  const int r0i = tid >> 2;
  const int cbs = (((tid & 3) ^ ((r0i >> 1) & 3))) * 8;

  floatx4 acc[4][4] = {};

  for (int k0 = 0; k0 < K; k0 += 32) {
    gld_lds16(X16 + (size_t)(m0 + r0i) * K + k0 + cbs, &As[tid * 8]);
    gld_lds16(X16 + (size_t)(m0 + 64 + r0i) * K + k0 + cbs, &As[(tid + 256) * 8]);
    gld_lds16(WqkvT + (size_t)(n0 + r0i) * K + k0 + cbs, &Bs[tid * 8]);
    gld_lds16(WqkvT + (size_t)(n0 + 64 + r0i) * K + k0 + cbs, &Bs[(tid + 256) * 8]);
    __syncthreads();
    half8v a[4], b[4];
    #pragma unroll
    for (int it = 0; it < 4; it++)
      a[it] = *(half8v*)&As[gswz(wr + it * 16 + l15, qd)];
    #pragma unroll
    for (int jt = 0; jt < 4; jt++)
      b[jt] = *(half8v*)&Bs[gswz(wc + jt * 16 + l15, qd)];
    #pragma unroll
    for (int it = 0; it < 4; it++)
      #pragma unroll
      for (int jt = 0; jt < 4; jt++)
        acc[it][jt] = MFMA16(a[it], b[jt], acc[it][jt]);
    __syncthreads();
  }

  if (n0 < 2048) {
    #pragma unroll
    for (int it = 0; it < 4; it++) {
      #pragma unroll
      for (int jt = 0; jt < 4; jt++) {
        #pragma unroll
        for (int r = 0; r < 4; r++) {
          int m = m0 + wr + it * 16 + qd * 4 + r;
          int n = n0 + wc + jt * 16 + l15;
          float val = acc[it][jt][r];
          int bb = m >> 11, nn = m & 2047;
          if (n0 < 1024) {
            int h = n >> 6, d = n & 63;
            q_ws[(((size_t)bb * 16 + h) * 2048 + nn) * 64 + d] = (_Float16)(val * QSCALE);
          } else {
            int c = n - 1024, h = c >> 6, d = c & 63;
            k_ws[(((size_t)bb * 16 + h) * 2048 + nn) * 64 + d] = (_Float16)val;
          }
        }
      }
    }
  } else {
    #pragma unroll
    for (int it = 0; it < 4; it++) {
      #pragma unroll
      for (int jt = 0; jt < 4; jt++) {
        #pragma unroll
        for (int r = 0; r < 4; r++) {
          int ml = wr + it * 16 + qd * 4 + r;
          int nl = wc + jt * 16 + l15;
          Tt[nl * 136 + ml] = (_Float16)acc[it][jt][r];
        }
      }
    }
    __syncthreads();
    int row = tid >> 1;
    int mh  = (tid & 1) * 64;
    int c   = (n0 - 2048) + row;
    int bb  = m0 >> 11;
    int nnb = (m0 & 2047) + mh;
    _Float16* dstp =
        vT_ws + (((size_t)bb * 16 + (c >> 6)) * 64 + (c & 63)) * 2048 + nnb;
    #pragma unroll
    for (int i = 0; i < 8; i++)
      *(half8v*)(dstp + i * 8) = *(half8v*)&Tt[row * 136 + mh + i * 8];
  }
}

// ---------------------------------------------------------------------------
// Kernel 2: flash attention v12 — direct global->VGPR K/V fragments.
// K[kv][d] and V^T[d][kv] fragment reads are 16B-contiguous per lane, so the
// whole LDS staging machinery for K/V is dropped. Only P round-trips via a
// wave-private 2KB LDS slot. 4 waves = q-split 2 x kv-split 2; each wave:
// 32 q-rows x (kv tiles stride 2). LDS 35KB -> 4 blocks/CU (16 waves = 33%
// occupancy) and a much shorter per-iter dependency chain; TLP hides L2
// latency. lsum on VALU (MFMA is the floor pipe). Epilogue: cross-wave (kw)
// reduction via LDS.
// ---------------------------------------------------------------------------
__global__ __launch_bounds__(256, 4) void attn_kernel(
    const _Float16* __restrict__ q_ws, const _Float16* __restrict__ k_ws,
    const _Float16* __restrict__ vT_ws, _Float16* __restrict__ aout)
{
  constexpr int N = 2048;
  // [0,8KB): P slots (4 waves x 2KB). [8KB,16KB): Q staging.
  // Epilogue overlay: [0,34KB): f32 partials 4 x [32][68]; [34KB,+512): ls.
  __shared__ alignas(16) char smem[35328];
  _Float16* Pbase = (_Float16*)smem;
  _Float16* Qs    = (_Float16*)(smem + 8192);

  const int id = blockIdx.x;
  const int bh = ((id >> 8) << 3) | (id & 7);
  const int qt = (id >> 3) & 31;

  const _Float16* Qp = q_ws + (size_t)bh * N * 64;
  const _Float16* Kp = k_ws + (size_t)bh * N * 64;
  const _Float16* Vp = vT_ws + (size_t)bh * 64 * N;

  const int tid = threadIdx.x, wave = tid >> 6, lane = tid & 63;
  const int qd = lane >> 4, l15 = lane & 15;
  const int q0 = qt * 64;
  const int qw = wave >> 1, kw = wave & 1;

  _Float16* Ps = Pbase + wave * 1024;   // wave-private 2KB P slot

  // Stage Q (64x64, swz) via gld_lds; all waves read their halves.
  #pragma unroll
  for (int i = 0; i < 2; i++) {
    int idx = tid + i * 256;
    int r = idx >> 3, cb = (idx ^ r) & 7;
    gld_lds16(Qp + (size_t)(q0 + r) * 64 + cb * 8, &Qs[idx * 8]);
  }
  __syncthreads();

  half8v qf[2][2];
  #pragma unroll
  for (int m = 0; m < 2; m++)
    #pragma unroll
    for (int ks = 0; ks < 2; ks++)
      qf[m][ks] = *(half8v*)&Qs[swz(qw * 32 + m * 16 + l15, ks * 4 + qd)];

  // This wave's kv stream: tiles (2*i + kw)*32, i = 0..31.
  const _Float16* Kw = Kp + (size_t)kw * 32 * 64;
  const _Float16* Vw = Vp + kw * 32;

  floatx4 o[2][4] = {};
  float lsum[2] = {0.f, 0.f};

  #pragma unroll 2
  for (int i = 0; i < 32; ++i) {
    const size_t kvg = (size_t)i * 64;   // row offset within this wave's stream

    // K fragments: A[kv=nt*16+l15][d=ks*32+qd*8+j], 16B contiguous.
    half8v kf[2][2];
    #pragma unroll
    for (int ks = 0; ks < 2; ks++)
      #pragma unroll
      for (int nt = 0; nt < 2; nt++)
        kf[ks][nt] = *(const half8v*)(Kw + (kvg + nt * 16 + l15) * 64 +
                                      (ks * 4 + qd) * 8);
    // V fragments: B[kv=qd*8+j][d=dt*16+l15] from V^T rows, 16B contiguous.
    half8v vf[4];
    #pragma unroll
    for (int dt = 0; dt < 4; dt++)
      vf[dt] = *(const half8v*)(Vw + (size_t)(dt * 16 + l15) * N + kvg + qd * 8);

    // S^T = K·Q^T : s[nt][m], kv = nt*16+qd*4+r, q = m*16+l15.
    floatx4 s[2][2] = {};
    __builtin_amdgcn_s_setprio(1);
    #pragma unroll
    for (int ks = 0; ks < 2; ks++)
      #pragma unroll
      for (int nt = 0; nt < 2; nt++)
        #pragma unroll
        for (int m = 0; m < 2; m++)
          s[nt][m] = MFMA16(kf[ks][nt], qf[m][ks], s[nt][m]);
    __builtin_amdgcn_s_setprio(0);

    // p = 2^s; VALU lsum; pack -> private P slot (vswz, 64B rows).
    #pragma unroll
    for (int m = 0; m < 2; m++)
      #pragma unroll
      for (int nt = 0; nt < 2; nt++) {
        float p0 = __builtin_amdgcn_exp2f(s[nt][m][0]);
        float p1 = __builtin_amdgcn_exp2f(s[nt][m][1]);
        float p2 = __builtin_amdgcn_exp2f(s[nt][m][2]);
        float p3 = __builtin_amdgcn_exp2f(s[nt][m][3]);
        lsum[m] += (p0 + p1) + (p2 + p3);
        half2v h01 = pk16(p0, p1);
        half2v h23 = pk16(p2, p3);
        half4v pk;
        pk[0] = h01[0]; pk[1] = h01[1]; pk[2] = h23[0]; pk[3] = h23[1];
        *(half4v*)&Ps[vswz(m * 16 + l15, 2 * nt + (qd >> 1)) + (qd & 1) * 4] = pk;
      }

    // O += P·V (pf: A[q=m*16+l15][kv=qd*8+j]).
    half8v pf[2];
    #pragma unroll
    for (int m = 0; m < 2; m++)
      pf[m] = *(half8v*)&Ps[vswz(m * 16 + l15, qd)];
    __builtin_amdgcn_s_setprio(1);
    #pragma unroll
    for (int m = 0; m < 2; m++)
      #pragma unroll
      for (int dt = 0; dt < 4; dt++)
        o[m][dt] = MFMA16(pf[m], vf[dt], o[m][dt]);
    __builtin_amdgcn_s_setprio(0);
  }

  // lsum: reduce over qd groups (q = m*16+l15 is constant across qd).
  #pragma unroll
  for (int m = 0; m < 2; m++) {
    lsum[m] += __shfl_xor(lsum[m], 16);
    lsum[m] += __shfl_xor(lsum[m], 32);
  }

  // ---- epilogue: cross-wave (kw) reduction through (dead) LDS ----
  __syncthreads();
  float* sc = (float*)smem;             // 4 slots x [32][68] f32 (stride 68)
  float* ls = (float*)(smem + 34816);   // [4][32] f32
  float* my = sc + wave * 2176;
  #pragma unroll
  for (int m = 0; m < 2; m++) {
    #pragma unroll
    for (int dt = 0; dt < 4; dt++)
      #pragma unroll
      for (int r = 0; r < 4; r++)
        my[(m * 16 + qd * 4 + r) * 68 + dt * 16 + l15] = o[m][dt][r];
    if (qd == 0) ls[wave * 32 + m * 16 + l15] = lsum[m];
  }
  __syncthreads();

  const int bb = bh >> 4, hh = bh & 15;
  const int row = tid >> 2, c0 = (tid & 3) * 16;
  const int qw2 = row >> 5, r32 = row & 31;
  const float* sa = sc + (qw2 * 2 + 0) * 2176 + r32 * 68 + c0;
  const float* sb = sc + (qw2 * 2 + 1) * 2176 + r32 * 68 + c0;
  float lsv = ls[(qw2 * 2 + 0) * 32 + r32] + ls[(qw2 * 2 + 1) * 32 + r32];
  float inv = 1.0f / lsv;
  _Float16 hv[16];
  #pragma unroll
  for (int j = 0; j < 4; j++) {
    floatx4 a = *(const floatx4*)(sa + j * 4);
    floatx4 b = *(const floatx4*)(sb + j * 4);
    floatx4 sum = a + b;
    half2v h01 = pk16(sum[0] * inv, sum[1] * inv);
    half2v h23 = pk16(sum[2] * inv, sum[3] * inv);
    hv[j * 4 + 0] = h01[0]; hv[j * 4 + 1] = h01[1];
    hv[j * 4 + 2] = h23[0]; hv[j * 4 + 3] = h23[1];
  }
  _Float16* dst = aout + ((size_t)(bb * 2048 + q0 + row)) * 1024 + hh * 64 + c0;
  *(half8v*)(dst)     = *(half8v*)&hv[0];
  *(half8v*)(dst + 8) = *(half8v*)&hv[8];
}

// ---------------------------------------------------------------------------
// Kernel 3: out projection (unchanged).
// ---------------------------------------------------------------------------
__global__ __launch_bounds__(256) void out_gemm(
    const _Float16* __restrict__ A, const _Float16* __restrict__ WoT,
    const float* __restrict__ bo, float* __restrict__ Out)
{
  constexpr int K = 1024;
  __shared__ alignas(16) _Float16 As[64 * 32];
  __shared__ alignas(16) _Float16 Bs[128 * 32];

  const int m0 = blockIdx.x * 64;
  const int n0 = blockIdx.y * 128;
  const int tid = threadIdx.x;
  const int wave = tid >> 6, lane = tid & 63;
  const int qd = lane >> 4, l15 = lane & 15;
  const int wr = (wave >> 1) * 32, wc = (wave & 1) * 64;
  const int r0i = tid >> 2;
  const int cbs = (((tid & 3) ^ ((r0i >> 1) & 3))) * 8;

  floatx4 acc[2][4] = {};

  for (int k0 = 0; k0 < K; k0 += 32) {
    gld_lds16(A + (size_t)(m0 + r0i) * K + k0 + cbs, &As[tid * 8]);
    gld_lds16(WoT + (size_t)(n0 + r0i) * K + k0 + cbs, &Bs[tid * 8]);
    gld_lds16(WoT + (size_t)(n0 + 64 + r0i) * K + k0 + cbs, &Bs[(tid + 256) * 8]);
    __syncthreads();
    half8v a[2], b[4];
    #pragma unroll
    for (int it = 0; it < 2; it++)
      a[it] = *(half8v*)&As[gswz(wr + it * 16 + l15, qd)];
    #pragma unroll
    for (int jt = 0; jt < 4; jt++)
      b[jt] = *(half8v*)&Bs[gswz(wc + jt * 16 + l15, qd)];
    #pragma unroll
    for (int it = 0; it < 2; it++)
      #pragma unroll
      for (int jt = 0; jt < 4; jt++)
        acc[it][jt] = MFMA16(a[it], b[jt], acc[it][jt]);
    __syncthreads();
  }

  #pragma unroll
  for (int it = 0; it < 2; it++) {
    #pragma unroll
    for (int jt = 0; jt < 4; jt++) {
      int n = n0 + wc + jt * 16 + l15;
      float bias = bo[n];
      #pragma unroll
      for (int r = 0; r < 4; r++) {
        int m = m0 + wr + it * 16 + qd * 4 + r;
        Out[(size_t)m * 1024 + n] = acc[it][jt][r] + bias;
      }
    }
  }
}

// ---------------------------------------------------------------------------
extern "C" void kernel_launch(void* const* d_in, const int* in_sizes, int n_in,
                              void* d_out, int out_size, void* d_ws, size_t ws_size,
                              hipStream_t stream) {
  const float* X   = (const float*)d_in[0];
  const float* Wq  = (const float*)d_in[1];
  const float* Wkv = (const float*)d_in[2];
  const float* Wo  = (const float*)d_in[3];
  const float* bo  = (const float*)d_in[4];
  float* out = (float*)d_out;

  const size_t M4 = (size_t)4 * 1024 * 1024;
  _Float16* q_ws   = (_Float16*)d_ws;
  _Float16* k_ws   = q_ws + M4;
  _Float16* vT_ws  = k_ws + M4;
  _Float16* X16    = vT_ws + M4;
  _Float16* WqkvT  = X16 + M4;
  _Float16* WoT    = WqkvT + (size_t)3 * 1024 * 1024;
  _Float16* aout   = X16;  // X16 dead after qkv_gemm

  prep<<<3072, 256, 0, stream>>>(X, Wq, Wkv, Wo, X16, WqkvT, WoT);
  qkv_gemm<<<dim3(32, 24), 256, 0, stream>>>(X16, WqkvT, q_ws, k_ws, vT_ws);
  attn_kernel<<<1024, 256, 0, stream>>>(q_ws, k_ws, vT_ws, aout);
  out_gemm<<<dim3(64, 8), 256, 0, stream>>>(aout, WoT, bo, out);
}

// Round 6
// 201.890 us; speedup vs baseline: 1.2330x; 1.2330x over previous
//
#include <hip/hip_runtime.h>
#include <math.h>
#include <stdint.h>

typedef _Float16 half8v __attribute__((ext_vector_type(8)));
typedef _Float16 half4v __attribute__((ext_vector_type(4)));
typedef _Float16 half2v __attribute__((ext_vector_type(2)));
typedef __fp16 fp16x2 __attribute__((ext_vector_type(2)));
typedef float floatx4 __attribute__((ext_vector_type(4)));

#define MFMA16(a, b, c) __builtin_amdgcn_mfma_f32_16x16x32_f16(a, b, c, 0, 0, 0)

// Q pre-scale: 1/sqrt(64) * log2(e), folded so attention uses exp2 directly.
#define QSCALE 0.18033688011112f

// Async global->LDS, 16B per lane. LDS dest must be wave-uniform base + lane*16;
// the GLOBAL source address is per-lane arbitrary (it's a gather).
__device__ __forceinline__ void gld_lds16(const void* g, void* l) {
  __builtin_amdgcn_global_load_lds(
      (const __attribute__((address_space(1))) uint32_t*)(uintptr_t)g,
      (__attribute__((address_space(3))) uint32_t*)(uintptr_t)l, 16, 0, 0);
}

// Packed f32x2 -> f16x2 (rtz), bit-cast to our _Float16 vector type.
__device__ __forceinline__ half2v pk16(float a, float b) {
  fp16x2 t = __builtin_amdgcn_cvt_pkrtz(a, b);
  return __builtin_bit_cast(half2v, t);
}

// LDS bank swizzle for 64-col fp16 tiles (128B rows), 16B blocks.
__device__ __forceinline__ int swz(int row, int blk) {
  return row * 64 + ((blk ^ (row & 7)) << 3);
}

// LDS bank swizzle for 32-col fp16 tiles (64B rows = 16 banks): XOR chunk
// with (row>>1)&3 so 16-row b128 frag reads are 2-way, not 8-way.
__device__ __forceinline__ int vswz(int row, int blk) {
  return row * 32 + ((blk ^ ((row >> 1) & 3)) << 3);
}

// GEMM 32-col tile swizzle (same math as vswz; kept separate for clarity).
__device__ __forceinline__ int gswz(int row, int blk) {
  return row * 32 + ((blk ^ ((row >> 1) & 3)) << 3);
}

// ---------------------------------------------------------------------------
// Prep (fused): blocks 0..2047 convert X fp32->fp16; blocks 2048..3071
// transpose+convert the weights.  (unchanged)
// ---------------------------------------------------------------------------
__global__ __launch_bounds__(256) void prep(
    const float* __restrict__ X, const float* __restrict__ Wq,
    const float* __restrict__ Wkv, const float* __restrict__ Wo,
    _Float16* __restrict__ X16, _Float16* __restrict__ WqkvT,
    _Float16* __restrict__ WoT)
{
  __shared__ alignas(16) _Float16 Tt[64 * 68];
  const int bid = blockIdx.x;
  if (bid < 2048) {
    size_t gid = (size_t)bid * 256 + threadIdx.x;
    const float4* src = (const float4*)(X) + gid * 2;
    float4 a = src[0], b = src[1];
    half8v h;
    h[0]=(_Float16)a.x; h[1]=(_Float16)a.y; h[2]=(_Float16)a.z; h[3]=(_Float16)a.w;
    h[4]=(_Float16)b.x; h[5]=(_Float16)b.y; h[6]=(_Float16)b.z; h[7]=(_Float16)b.w;
    *((half8v*)X16 + gid) = h;
    return;
  }
  int b = bid - 2048;
  const float* src; _Float16* dst; int N, tk, tn;
  if (b < 256)      { src = Wq;  dst = WqkvT;                 N = 1024; tk = b & 15;        tn = b >> 4; }
  else if (b < 768) { src = Wkv; dst = WqkvT + (size_t)1024 * 1024; N = 2048; tk = (b - 256) & 15; tn = (b - 256) >> 4; }
  else              { src = Wo;  dst = WoT;                   N = 1024; tk = (b - 768) & 15; tn = (b - 768) >> 4; }

  const int t = threadIdx.x;
  {
    int kg = t >> 4, ng = t & 15;
    const float* sp = src + (size_t)(tk * 64 + kg * 4) * N + tn * 64 + ng * 4;
    float4 r0 = *(const float4*)(sp);
    float4 r1 = *(const float4*)(sp + N);
    float4 r2 = *(const float4*)(sp + 2 * N);
    float4 r3 = *(const float4*)(sp + 3 * N);
    half4v h;
    h[0]=(_Float16)r0.x; h[1]=(_Float16)r1.x; h[2]=(_Float16)r2.x; h[3]=(_Float16)r3.x;
    *(half4v*)&Tt[(ng * 4 + 0) * 68 + kg * 4] = h;
    h[0]=(_Float16)r0.y; h[1]=(_Float16)r1.y; h[2]=(_Float16)r2.y; h[3]=(_Float16)r3.y;
    *(half4v*)&Tt[(ng * 4 + 1) * 68 + kg * 4] = h;
    h[0]=(_Float16)r0.z; h[1]=(_Float16)r1.z; h[2]=(_Float16)r2.z; h[3]=(_Float16)r3.z;
    *(half4v*)&Tt[(ng * 4 + 2) * 68 + kg * 4] = h;
    h[0]=(_Float16)r0.w; h[1]=(_Float16)r1.w; h[2]=(_Float16)r2.w; h[3]=(_Float16)r3.w;
    *(half4v*)&Tt[(ng * 4 + 3) * 68 + kg * 4] = h;
  }
  __syncthreads();
  #pragma unroll
  for (int i = 0; i < 2; i++) {
    int idx = t + i * 256;
    int nl = idx >> 3, k8 = (idx & 7) * 8;
    half8v v = *(half8v*)&Tt[nl * 68 + k8];
    *(half8v*)(dst + (size_t)(tn * 64 + nl) * 1024 + tk * 64 + k8) = v;
  }
}

// ---------------------------------------------------------------------------
// Kernel 1: QKV projection (unchanged: m97 structure + gswz).
// ---------------------------------------------------------------------------
__global__ __launch_bounds__(256) void qkv_gemm(
    const _Float16* __restrict__ X16, const _Float16* __restrict__ WqkvT,
    _Float16* __restrict__ q_ws, _Float16* __restrict__ k_ws,
    _Float16* __restrict__ vT_ws)
{
  constexpr int K = 1024;
  __shared__ alignas(16) _Float16 Tt[128 * 136];
  _Float16* As = Tt;
  _Float16* Bs = Tt + 4096;

  const int m0 = blockIdx.x * 128;
  const int n0 = blockIdx.y * 128;

  const int tid  = threadIdx.x;
  const int wave = tid >> 6, lane = tid & 63;
  const int qd = lane >> 4, l15 = lane & 15;
  const int wr = (wave >> 1) * 64, wc = (wave & 1) * 64;
  const int r0i = tid >> 2;
  const int cbs = (((tid & 3) ^ ((r0i >> 1) & 3))) * 8;

  floatx4 acc[4][4] = {};

  for (int k0 = 0; k0 < K; k0 += 32) {
    gld_lds16(X16 + (size_t)(m0 + r0i) * K + k0 + cbs, &As[tid * 8]);
    gld_lds16(X16 + (size_t)(m0 + 64 + r0i) * K + k0 + cbs, &As[(tid + 256) * 8]);
    gld_lds16(WqkvT + (size_t)(n0 + r0i) * K + k0 + cbs, &Bs[tid * 8]);
    gld_lds16(WqkvT + (size_t)(n0 + 64 + r0i) * K + k0 + cbs, &Bs[(tid + 256) * 8]);
    __syncthreads();
    half8v a[4], b[4];
    #pragma unroll
    for (int it = 0; it < 4; it++)
      a[it] = *(half8v*)&As[gswz(wr + it * 16 + l15, qd)];
    #pragma unroll
    for (int jt = 0; jt < 4; jt++)
      b[jt] = *(half8v*)&Bs[gswz(wc + jt * 16 + l15, qd)];
    #pragma unroll
    for (int it = 0; it < 4; it++)
      #pragma unroll
      for (int jt = 0; jt < 4; jt++)
        acc[it][jt] = MFMA16(a[it], b[jt], acc[it][jt]);
    __syncthreads();
  }

  if (n0 < 2048) {
    #pragma unroll
    for (int it = 0; it < 4; it++) {
      #pragma unroll
      for (int jt = 0; jt < 4; jt++) {
        #pragma unroll
        for (int r = 0; r < 4; r++) {
          int m = m0 + wr + it * 16 + qd * 4 + r;
          int n = n0 + wc + jt * 16 + l15;
          float val = acc[it][jt][r];
          int bb = m >> 11, nn = m & 2047;
          if (n0 < 1024) {
            int h = n >> 6, d = n & 63;
            q_ws[(((size_t)bb * 16 + h) * 2048 + nn) * 64 + d] = (_Float16)(val * QSCALE);
          } else {
            int c = n - 1024, h = c >> 6, d = c & 63;
            k_ws[(((size_t)bb * 16 + h) * 2048 + nn) * 64 + d] = (_Float16)val;
          }
        }
      }
    }
  } else {
    #pragma unroll
    for (int it = 0; it < 4; it++) {
      #pragma unroll
      for (int jt = 0; jt < 4; jt++) {
        #pragma unroll
        for (int r = 0; r < 4; r++) {
          int ml = wr + it * 16 + qd * 4 + r;
          int nl = wc + jt * 16 + l15;
          Tt[nl * 136 + ml] = (_Float16)acc[it][jt][r];
        }
      }
    }
    __syncthreads();
    int row = tid >> 1;
    int mh  = (tid & 1) * 64;
    int c   = (n0 - 2048) + row;
    int bb  = m0 >> 11;
    int nnb = (m0 & 2047) + mh;
    _Float16* dstp =
        vT_ws + (((size_t)bb * 16 + (c >> 6)) * 64 + (c & 63)) * 2048 + nnb;
    #pragma unroll
    for (int i = 0; i < 8; i++)
      *(half8v*)(dstp + i * 8) = *(half8v*)&Tt[row * 136 + mh + i * 8];
  }
}

// ---------------------------------------------------------------------------
// Kernel 2: flash attention v13 — v11 dataflow at 3 blocks/CU.
// Split-kv across 4 waves (each: 64 q-rows x 16 stride-4 tiles of 32 kv),
// barrier-free counted-vmcnt loop, coalesced staging. LDS 65KB -> 49KB:
//   K: SINGLE 4KB/wave buffer; next tile prefetched into 4 VGPR x b128 via
//      coalesced global loads, ds_written (swizzled) after this tile's reads.
//   V: single 4KB/wave gld_lds (v11 flow).  P: 4KB/wave (Q overlays at start).
// lsum on VALU (drops the ones-column MFMA: -11% MFMA ops).
// Per-iter per-wave vmcnt choreography (gld_lds + kreg loads both count):
//   entry in-flight: [V(i) x4 glds, Kreg(i+1) x4 loads]
//   QK^T from K(i) LDS -> exp2/P-write -> vmcnt(4) [V(i) ready]
//   pf/vf ds_reads -> lgkmcnt(0) [WAR-safe] -> ds_write K(i+1) (compiler
//   waits kreg) -> issue V(i+1) glds, Kreg(i+2) loads -> PV MFMA.
// Epilogue: two 32-row passes of cross-wave reduction via (dead) LDS.
// ---------------------------------------------------------------------------
__global__ __launch_bounds__(256, 3) void attn_kernel(
    const _Float16* __restrict__ q_ws, const _Float16* __restrict__ k_ws,
    const _Float16* __restrict__ vT_ws, _Float16* __restrict__ aout)
{
  constexpr int N = 2048;
  // [0,16K): K 4 x 4KB | [16K,32K): V 4 x 4KB | [32K,48K): P 4 x 4KB (Q first)
  // [48K,49K): ls. Epilogue overlay: sc = 4 x [32][68] f32 (34816B) at base.
  __shared__ alignas(16) char smem[50176];
  _Float16* Kbase = (_Float16*)smem;
  _Float16* Vbase = (_Float16*)(smem + 16384);
  _Float16* PQ    = (_Float16*)(smem + 32768);

  const int id = blockIdx.x;
  const int bh = ((id >> 8) << 3) | (id & 7);
  const int qt = (id >> 3) & 31;

  const _Float16* Qp = q_ws + (size_t)bh * N * 64;
  const _Float16* Kp = k_ws + (size_t)bh * N * 64;
  const _Float16* Vp = vT_ws + (size_t)bh * 64 * N;

  const int tid = threadIdx.x, wave = tid >> 6, lane = tid & 63;
  const int qd = lane >> 4, l15 = lane & 15;
  const int q0 = qt * 64;
  const int wkv = wave * 32;   // this wave's kv offset within a 128-row stride

  _Float16* Ks = Kbase + wave * 2048;   // private 4KB K buffer
  _Float16* Vs = Vbase + wave * 2048;   // private 4KB V buffer
  _Float16* Ps = PQ + wave * 2048;      // private 4KB P slot

  // staging lane constants
  const int krr = lane >> 3, kcb = (lane & 7) ^ krr;               // K gld_lds
  const int vrr = lane >> 2, vcb = (lane & 3) ^ ((lane >> 3) & 3); // V gld_lds
  // K reg-stage: linear coalesced load; swizzled ds_write target.
  const int kwr = (krr * 64 + (kcb << 3));  // halves offset within tile row grp

  auto stage_v = [&](int il) {
    const _Float16* src = Vp + wkv + il * 128;
    #pragma unroll
    for (int j = 0; j < 4; j++)
      gld_lds16(src + (size_t)(j * 16 + vrr) * N + vcb * 8,
                Vs + (j * 64 + lane) * 8);
  };

  // Prologue: Q (2 gld_lds/thread) + K0 (gld_lds) + V0 (gld_lds) + Kreg(1).
  #pragma unroll
  for (int i = 0; i < 2; i++) {
    int idx = tid + i * 256;
    int r = idx >> 3, cb = (idx ^ r) & 7;
    gld_lds16(Qp + (size_t)(q0 + r) * 64 + cb * 8, PQ + idx * 8);
  }
  {
    const _Float16* src = Kp + (size_t)wkv * 64;   // tile 0
    #pragma unroll
    for (int j = 0; j < 4; j++)
      gld_lds16(src + (size_t)(j * 8 + krr) * 64 + kcb * 8,
                Ks + (j * 64 + lane) * 8);
  }
  stage_v(0);
  const _Float16* Kw = Kp + (size_t)wkv * 64;      // wave's tile-0 base
  half8v kr0, kr1, kr2, kr3;
  {
    const _Float16* nb = Kw + (size_t)1 * 8192 + lane * 8;  // tile 1, linear
    kr0 = *(const half8v*)(nb);
    kr1 = *(const half8v*)(nb + 512);
    kr2 = *(const half8v*)(nb + 1024);
    kr3 = *(const half8v*)(nb + 1536);
  }

  asm volatile("s_waitcnt vmcnt(8)" ::: "memory");  // Q + K0 resident (own)
  __builtin_amdgcn_s_barrier();                     // Q resident (all waves)
  __builtin_amdgcn_sched_barrier(0);

  half8v qf[4][2];
  #pragma unroll
  for (int m = 0; m < 4; m++)
    #pragma unroll
    for (int ks = 0; ks < 2; ks++)
      qf[m][ks] = *(half8v*)&PQ[swz(m * 16 + l15, ks * 4 + qd)];

  asm volatile("s_waitcnt lgkmcnt(0)" ::: "memory");  // qf in regs
  __builtin_amdgcn_s_barrier();                       // before P overwrites Q
  __builtin_amdgcn_sched_barrier(0);

  floatx4 o[4][4] = {};
  float lsum[4] = {};

  for (int i = 0; i < 16; ++i) {
    // S^T = K·Q^T : s[nt][m], kv = nt*16+qd*4+r, q = m*16+l15.
    floatx4 s[2][4] = {};
    #pragma unroll
    for (int ks = 0; ks < 2; ks++) {
      half8v kf0 = *(half8v*)&Ks[swz(l15, ks * 4 + qd)];
      half8v kf1 = *(half8v*)&Ks[swz(16 + l15, ks * 4 + qd)];
      __builtin_amdgcn_s_setprio(1);
      #pragma unroll
      for (int m = 0; m < 4; m++) {
        s[0][m] = MFMA16(kf0, qf[m][ks], s[0][m]);
        s[1][m] = MFMA16(kf1, qf[m][ks], s[1][m]);
      }
      __builtin_amdgcn_s_setprio(0);
    }

    // p = 2^s; VALU lsum; pack -> private P slot (vswz).
    #pragma unroll
    for (int m = 0; m < 4; m++)
      #pragma unroll
      for (int nt = 0; nt < 2; nt++) {
        float p0 = __builtin_amdgcn_exp2f(s[nt][m][0]);
        float p1 = __builtin_amdgcn_exp2f(s[nt][m][1]);
        float p2 = __builtin_amdgcn_exp2f(s[nt][m][2]);
        float p3 = __builtin_amdgcn_exp2f(s[nt][m][3]);
        lsum[m] += (p0 + p1) + (p2 + p3);
        half2v h01 = pk16(p0, p1);
        half2v h23 = pk16(p2, p3);
        half4v pk;
        pk[0] = h01[0]; pk[1] = h01[1]; pk[2] = h23[0]; pk[3] = h23[1];
        *(half4v*)&Ps[vswz(m * 16 + l15, 2 * nt + (qd >> 1)) + (qd & 1) * 4] = pk;
      }

    // V(i) resident (leaves Kreg(i+1) in flight).
    if (i < 15) asm volatile("s_waitcnt vmcnt(4)" ::: "memory");
    else        asm volatile("s_waitcnt vmcnt(0)" ::: "memory");
    __builtin_amdgcn_sched_barrier(0);

    half8v pf[4], vf[4];
    #pragma unroll
    for (int m = 0; m < 4; m++)
      pf[m] = *(half8v*)&Ps[vswz(m * 16 + l15, qd)];
    #pragma unroll
    for (int dt = 0; dt < 4; dt++)
      vf[dt] = *(half8v*)&Vs[vswz(dt * 16 + l15, qd)];

    asm volatile("s_waitcnt lgkmcnt(0)" ::: "memory");  // reads done -> WAR-safe
    __builtin_amdgcn_sched_barrier(0);

    // ds_write K(i+1) from regs (compiler inserts the kreg vmcnt wait).
    if (i < 15) {
      _Float16* wr = Ks + kwr;
      *(half8v*)(wr)        = kr0;
      *(half8v*)(wr + 512)  = kr1;
      *(half8v*)(wr + 1024) = kr2;
      *(half8v*)(wr + 1536) = kr3;
    }
    __builtin_amdgcn_sched_barrier(0);

    // Issue V(i+1) gld_lds, then Kreg(i+2) loads (order matters for counts).
    if (i < 15) stage_v(i + 1);
    if (i < 14) {
      const _Float16* nb = Kw + (size_t)(i + 2) * 8192 + lane * 8;
      kr0 = *(const half8v*)(nb);
      kr1 = *(const half8v*)(nb + 512);
      kr2 = *(const half8v*)(nb + 1024);
      kr3 = *(const half8v*)(nb + 1536);
    }
    __builtin_amdgcn_sched_barrier(0);

    // O += P·V.
    __builtin_amdgcn_s_setprio(1);
    #pragma unroll
    for (int m = 0; m < 4; m++)
      #pragma unroll
      for (int dt = 0; dt < 4; dt++)
        o[m][dt] = MFMA16(pf[m], vf[dt], o[m][dt]);
    __builtin_amdgcn_s_setprio(0);
  }

  // lsum: reduce across qd groups (q = m*16+l15 constant across qd).
  #pragma unroll
  for (int m = 0; m < 4; m++) {
    lsum[m] += __shfl_xor(lsum[m], 16);
    lsum[m] += __shfl_xor(lsum[m], 32);
  }

  // ---- epilogue: cross-wave reduction via (dead) LDS, two 32-row passes ----
  __syncthreads();                       // all waves done with K/V/P
  float* sc = (float*)smem;              // 4 x [32][68] f32 = 34816B
  float* ls = (float*)(smem + 49152);    // [4][64] f32
  #pragma unroll
  for (int m = 0; m < 4; m++)
    if (qd == 0) ls[wave * 64 + m * 16 + l15] = lsum[m];

  const int bb = bh >> 4, hh = bh & 15;
  #pragma unroll
  for (int pass = 0; pass < 2; pass++) {
    float* my = sc + wave * 2176;
    #pragma unroll
    for (int mm = 0; mm < 2; mm++) {
      int m = pass * 2 + mm;
      #pragma unroll
      for (int dt = 0; dt < 4; dt++)
        #pragma unroll
        for (int r = 0; r < 4; r++)
          my[(mm * 16 + qd * 4 + r) * 68 + dt * 16 + l15] = o[m][dt][r];
    }
    __syncthreads();
    {
      int r = tid >> 3, c0 = (tid & 7) * 8;
      int row = pass * 32 + r;
      float lsv = ls[row] + ls[64 + row] + ls[128 + row] + ls[192 + row];
      float inv = 1.0f / lsv;
      float acc8[8] = {};
      #pragma unroll
      for (int w = 0; w < 4; w++) {
        const float* p = sc + w * 2176 + r * 68 + c0;
        floatx4 a = *(const floatx4*)(p);
        floatx4 b = *(const floatx4*)(p + 4);
        acc8[0] += a[0]; acc8[1] += a[1]; acc8[2] += a[2]; acc8[3] += a[3];
        acc8[4] += b[0]; acc8[5] += b[1]; acc8[6] += b[2]; acc8[7] += b[3];
      }
      _Float16 hv[8];
      #pragma unroll
      for (int j = 0; j < 4; j++) {
        half2v h = pk16(acc8[2 * j] * inv, acc8[2 * j + 1] * inv);
        hv[2 * j] = h[0]; hv[2 * j + 1] = h[1];
      }
      _Float16* dst =
          aout + ((size_t)(bb * 2048 + q0 + row)) * 1024 + hh * 64 + c0;
      *(half8v*)dst = *(half8v*)hv;
    }
    if (pass == 0) __syncthreads();
  }
}

// ---------------------------------------------------------------------------
// Kernel 3: out projection (unchanged).
// ---------------------------------------------------------------------------
__global__ __launch_bounds__(256) void out_gemm(
    const _Float16* __restrict__ A, const _Float16* __restrict__ WoT,
    const float* __restrict__ bo, float* __restrict__ Out)
{
  constexpr int K = 1024;
  __shared__ alignas(16) _Float16 As[64 * 32];
  __shared__ alignas(16) _Float16 Bs[128 * 32];

  const int m0 = blockIdx.x * 64;
  const int n0 = blockIdx.y * 128;
  const int tid = threadIdx.x;
  const int wave = tid >> 6, lane = tid & 63;
  const int qd = lane >> 4, l15 = lane & 15;
  const int wr = (wave >> 1) * 32, wc = (wave & 1) * 64;
  const int r0i = tid >> 2;
  const int cbs = (((tid & 3) ^ ((r0i >> 1) & 3))) * 8;

  floatx4 acc[2][4] = {};

  for (int k0 = 0; k0 < K; k0 += 32) {
    gld_lds16(A + (size_t)(m0 + r0i) * K + k0 + cbs, &As[tid * 8]);
    gld_lds16(WoT + (size_t)(n0 + r0i) * K + k0 + cbs, &Bs[tid * 8]);
    gld_lds16(WoT + (size_t)(n0 + 64 + r0i) * K + k0 + cbs, &Bs[(tid + 256) * 8]);
    __syncthreads();
    half8v a[2], b[4];
    #pragma unroll
    for (int it = 0; it < 2; it++)
      a[it] = *(half8v*)&As[gswz(wr + it * 16 + l15, qd)];
    #pragma unroll
    for (int jt = 0; jt < 4; jt++)
      b[jt] = *(half8v*)&Bs[gswz(wc + jt * 16 + l15, qd)];
    #pragma unroll
    for (int it = 0; it < 2; it++)
      #pragma unroll
      for (int jt = 0; jt < 4; jt++)
        acc[it][jt] = MFMA16(a[it], b[jt], acc[it][jt]);
    __syncthreads();
  }

  #pragma unroll
  for (int it = 0; it < 2; it++) {
    #pragma unroll
    for (int jt = 0; jt < 4; jt++) {
      int n = n0 + wc + jt * 16 + l15;
      float bias = bo[n];
      #pragma unroll
      for (int r = 0; r < 4; r++) {
        int m = m0 + wr + it * 16 + qd * 4 + r;
        Out[(size_t)m * 1024 + n] = acc[it][jt][r] + bias;
      }
    }
  }
}

// ---------------------------------------------------------------------------
extern "C" void kernel_launch(void* const* d_in, const int* in_sizes, int n_in,
                              void* d_out, int out_size, void* d_ws, size_t ws_size,
                              hipStream_t stream) {
  const float* X   = (const float*)d_in[0];
  const float* Wq  = (const float*)d_in[1];
  const float* Wkv = (const float*)d_in[2];
  const float* Wo  = (const float*)d_in[3];
  const float* bo  = (const float*)d_in[4];
  float* out = (float*)d_out;

  const size_t M4 = (size_t)4 * 1024 * 1024;
  _Float16* q_ws   = (_Float16*)d_ws;
  _Float16* k_ws   = q_ws + M4;
  _Float16* vT_ws  = k_ws + M4;
  _Float16* X16    = vT_ws + M4;
  _Float16* WqkvT  = X16 + M4;
  _Float16* WoT    = WqkvT + (size_t)3 * 1024 * 1024;
  _Float16* aout   = X16;  // X16 dead after qkv_gemm

  prep<<<3072, 256, 0, stream>>>(X, Wq, Wkv, Wo, X16, WqkvT, WoT);
  qkv_gemm<<<dim3(32, 24), 256, 0, stream>>>(X16, WqkvT, q_ws, k_ws, vT_ws);
  attn_kernel<<<1024, 256, 0, stream>>>(q_ws, k_ws, vT_ws, aout);
  out_gemm<<<dim3(64, 8), 256, 0, stream>>>(aout, WoT, bo, out);
}

// Round 7
// 178.402 us; speedup vs baseline: 1.3953x; 1.1317x over previous
//
#include <hip/hip_runtime.h>
#include <math.h>
#include <stdint.h>

typedef _Float16 half8v __attribute__((ext_vector_type(8)));
typedef _Float16 half4v __attribute__((ext_vector_type(4)));
typedef _Float16 half2v __attribute__((ext_vector_type(2)));
typedef __fp16 fp16x2 __attribute__((ext_vector_type(2)));
typedef float floatx4 __attribute__((ext_vector_type(4)));

#define MFMA16(a, b, c) __builtin_amdgcn_mfma_f32_16x16x32_f16(a, b, c, 0, 0, 0)

// Q pre-scale: 1/sqrt(64) * log2(e), folded so attention uses exp2 directly.
#define QSCALE 0.18033688011112f

// Async global->LDS, 16B per lane. LDS dest must be wave-uniform base + lane*16;
// the GLOBAL source address is per-lane arbitrary (it's a gather).
__device__ __forceinline__ void gld_lds16(const void* g, void* l) {
  __builtin_amdgcn_global_load_lds(
      (const __attribute__((address_space(1))) uint32_t*)(uintptr_t)g,
      (__attribute__((address_space(3))) uint32_t*)(uintptr_t)l, 16, 0, 0);
}

// Packed f32x2 -> f16x2 (rtz), bit-cast to our _Float16 vector type.
__device__ __forceinline__ half2v pk16(float a, float b) {
  fp16x2 t = __builtin_amdgcn_cvt_pkrtz(a, b);
  return __builtin_bit_cast(half2v, t);
}

// LDS bank swizzle for 64-col fp16 tiles (128B rows), 16B blocks.
__device__ __forceinline__ int swz(int row, int blk) {
  return row * 64 + ((blk ^ (row & 7)) << 3);
}

// LDS bank swizzle for 32-col fp16 tiles (64B rows = 16 banks): XOR chunk
// with (row>>1)&3 so 16-row b128 frag reads are 2-way, not 8-way.
__device__ __forceinline__ int vswz(int row, int blk) {
  return row * 32 + ((blk ^ ((row >> 1) & 3)) << 3);
}

// GEMM 32-col tile swizzle (same math as vswz; kept separate for clarity).
__device__ __forceinline__ int gswz(int row, int blk) {
  return row * 32 + ((blk ^ ((row >> 1) & 3)) << 3);
}

// ---------------------------------------------------------------------------
// Prep (fused): blocks 0..2047 convert X fp32->fp16; blocks 2048..3071
// transpose+convert the weights.  (unchanged)
// ---------------------------------------------------------------------------
__global__ __launch_bounds__(256) void prep(
    const float* __restrict__ X, const float* __restrict__ Wq,
    const float* __restrict__ Wkv, const float* __restrict__ Wo,
    _Float16* __restrict__ X16, _Float16* __restrict__ WqkvT,
    _Float16* __restrict__ WoT)
{
  __shared__ alignas(16) _Float16 Tt[64 * 68];
  const int bid = blockIdx.x;
  if (bid < 2048) {
    size_t gid = (size_t)bid * 256 + threadIdx.x;
    const float4* src = (const float4*)(X) + gid * 2;
    float4 a = src[0], b = src[1];
    half8v h;
    h[0]=(_Float16)a.x; h[1]=(_Float16)a.y; h[2]=(_Float16)a.z; h[3]=(_Float16)a.w;
    h[4]=(_Float16)b.x; h[5]=(_Float16)b.y; h[6]=(_Float16)b.z; h[7]=(_Float16)b.w;
    *((half8v*)X16 + gid) = h;
    return;
  }
  int b = bid - 2048;
  const float* src; _Float16* dst; int N, tk, tn;
  if (b < 256)      { src = Wq;  dst = WqkvT;                 N = 1024; tk = b & 15;        tn = b >> 4; }
  else if (b < 768) { src = Wkv; dst = WqkvT + (size_t)1024 * 1024; N = 2048; tk = (b - 256) & 15; tn = (b - 256) >> 4; }
  else              { src = Wo;  dst = WoT;                   N = 1024; tk = (b - 768) & 15; tn = (b - 768) >> 4; }

  const int t = threadIdx.x;
  {
    int kg = t >> 4, ng = t & 15;
    const float* sp = src + (size_t)(tk * 64 + kg * 4) * N + tn * 64 + ng * 4;
    float4 r0 = *(const float4*)(sp);
    float4 r1 = *(const float4*)(sp + N);
    float4 r2 = *(const float4*)(sp + 2 * N);
    float4 r3 = *(const float4*)(sp + 3 * N);
    half4v h;
    h[0]=(_Float16)r0.x; h[1]=(_Float16)r1.x; h[2]=(_Float16)r2.x; h[3]=(_Float16)r3.x;
    *(half4v*)&Tt[(ng * 4 + 0) * 68 + kg * 4] = h;
    h[0]=(_Float16)r0.y; h[1]=(_Float16)r1.y; h[2]=(_Float16)r2.y; h[3]=(_Float16)r3.y;
    *(half4v*)&Tt[(ng * 4 + 1) * 68 + kg * 4] = h;
    h[0]=(_Float16)r0.z; h[1]=(_Float16)r1.z; h[2]=(_Float16)r2.z; h[3]=(_Float16)r3.z;
    *(half4v*)&Tt[(ng * 4 + 2) * 68 + kg * 4] = h;
    h[0]=(_Float16)r0.w; h[1]=(_Float16)r1.w; h[2]=(_Float16)r2.w; h[3]=(_Float16)r3.w;
    *(half4v*)&Tt[(ng * 4 + 3) * 68 + kg * 4] = h;
  }
  __syncthreads();
  #pragma unroll
  for (int i = 0; i < 2; i++) {
    int idx = t + i * 256;
    int nl = idx >> 3, k8 = (idx & 7) * 8;
    half8v v = *(half8v*)&Tt[nl * 68 + k8];
    *(half8v*)(dst + (size_t)(tn * 64 + nl) * 1024 + tk * 64 + k8) = v;
  }
}

// ---------------------------------------------------------------------------
// Kernel 1: QKV projection (unchanged: m97 structure + gswz).
// ---------------------------------------------------------------------------
__global__ __launch_bounds__(256) void qkv_gemm(
    const _Float16* __restrict__ X16, const _Float16* __restrict__ WqkvT,
    _Float16* __restrict__ q_ws, _Float16* __restrict__ k_ws,
    _Float16* __restrict__ vT_ws)
{
  constexpr int K = 1024;
  __shared__ alignas(16) _Float16 Tt[128 * 136];
  _Float16* As = Tt;
  _Float16* Bs = Tt + 4096;

  const int m0 = blockIdx.x * 128;
  const int n0 = blockIdx.y * 128;

  const int tid  = threadIdx.x;
  const int wave = tid >> 6, lane = tid & 63;
  const int qd = lane >> 4, l15 = lane & 15;
  const int wr = (wave >> 1) * 64, wc = (wave & 1) * 64;
  const int r0i = tid >> 2;
  const int cbs = (((tid & 3) ^ ((r0i >> 1) & 3))) * 8;

  floatx4 acc[4][4] = {};

  for (int k0 = 0; k0 < K; k0 += 32) {
    gld_lds16(X16 + (size_t)(m0 + r0i) * K + k0 + cbs, &As[tid * 8]);
    gld_lds16(X16 + (size_t)(m0 + 64 + r0i) * K + k0 + cbs, &As[(tid + 256) * 8]);
    gld_lds16(WqkvT + (size_t)(n0 + r0i) * K + k0 + cbs, &Bs[tid * 8]);
    gld_lds16(WqkvT + (size_t)(n0 + 64 + r0i) * K + k0 + cbs, &Bs[(tid + 256) * 8]);
    __syncthreads();
    half8v a[4], b[4];
    #pragma unroll
    for (int it = 0; it < 4; it++)
      a[it] = *(half8v*)&As[gswz(wr + it * 16 + l15, qd)];
    #pragma unroll
    for (int jt = 0; jt < 4; jt++)
      b[jt] = *(half8v*)&Bs[gswz(wc + jt * 16 + l15, qd)];
    #pragma unroll
    for (int it = 0; it < 4; it++)
      #pragma unroll
      for (int jt = 0; jt < 4; jt++)
        acc[it][jt] = MFMA16(a[it], b[jt], acc[it][jt]);
    __syncthreads();
  }

  if (n0 < 2048) {
    #pragma unroll
    for (int it = 0; it < 4; it++) {
      #pragma unroll
      for (int jt = 0; jt < 4; jt++) {
        #pragma unroll
        for (int r = 0; r < 4; r++) {
          int m = m0 + wr + it * 16 + qd * 4 + r;
          int n = n0 + wc + jt * 16 + l15;
          float val = acc[it][jt][r];
          int bb = m >> 11, nn = m & 2047;
          if (n0 < 1024) {
            int h = n >> 6, d = n & 63;
            q_ws[(((size_t)bb * 16 + h) * 2048 + nn) * 64 + d] = (_Float16)(val * QSCALE);
          } else {
            int c = n - 1024, h = c >> 6, d = c & 63;
            k_ws[(((size_t)bb * 16 + h) * 2048 + nn) * 64 + d] = (_Float16)val;
          }
        }
      }
    }
  } else {
    #pragma unroll
    for (int it = 0; it < 4; it++) {
      #pragma unroll
      for (int jt = 0; jt < 4; jt++) {
        #pragma unroll
        for (int r = 0; r < 4; r++) {
          int ml = wr + it * 16 + qd * 4 + r;
          int nl = wc + jt * 16 + l15;
          Tt[nl * 136 + ml] = (_Float16)acc[it][jt][r];
        }
      }
    }
    __syncthreads();
    int row = tid >> 1;
    int mh  = (tid & 1) * 64;
    int c   = (n0 - 2048) + row;
    int bb  = m0 >> 11;
    int nnb = (m0 & 2047) + mh;
    _Float16* dstp =
        vT_ws + (((size_t)bb * 16 + (c >> 6)) * 64 + (c & 63)) * 2048 + nnb;
    #pragma unroll
    for (int i = 0; i < 8; i++)
      *(half8v*)(dstp + i * 8) = *(half8v*)&Tt[row * 136 + mh + i * 8];
  }
}

// ---------------------------------------------------------------------------
// Kernel 2: flash attention v14 = v11 (proven 52.6us) with lsum on VALU.
// Split-kv across 4 waves, private K-dbuf/V/P buffers, barrier-free
// counted-vmcnt loop. The ones-column MFMA is dropped (-11% MFMA ops);
// lsum accumulates on the VALU during the exp2 pass (validated in R2/v13).
// ---------------------------------------------------------------------------
__global__ __launch_bounds__(256, 2) void attn_kernel(
    const _Float16* __restrict__ q_ws, const _Float16* __restrict__ k_ws,
    const _Float16* __restrict__ vT_ws, _Float16* __restrict__ aout)
{
  constexpr int N = 2048;
  // 65KB: K slots [4w][2][2048] | V slots [4w][2048] | PQ [4w][2048] | lsum 1KB
  __shared__ alignas(16) char smem[66560];
  _Float16* Kbase = (_Float16*)smem;                  // 32KB
  _Float16* Vbase = (_Float16*)(smem + 32768);        // 16KB
  _Float16* PQ    = (_Float16*)(smem + 49152);        // 16KB

  const int id = blockIdx.x;
  const int bh = ((id >> 8) << 3) | (id & 7);
  const int qt = (id >> 3) & 31;

  const _Float16* Qp = q_ws + (size_t)bh * N * 64;
  const _Float16* Kp = k_ws + (size_t)bh * N * 64;
  const _Float16* Vp = vT_ws + (size_t)bh * 64 * N;

  const int tid = threadIdx.x, wave = tid >> 6, lane = tid & 63;
  const int qd = lane >> 4, l15 = lane & 15;
  const int q0 = qt * 64;
  const int wkv = wave * 32;        // this wave's kv offset within a stride

  _Float16* Ps = PQ + wave * 2048;          // private P slot (4KB)
  _Float16* Vs = Vbase + wave * 2048;       // private V slot (4KB)

  // per-wave staging lane constants
  const int krr = lane >> 3, kcb = (lane & 7) ^ krr;            // K: 8 rows/gld
  const int vrr = lane >> 2, vcb = (lane & 3) ^ ((lane >> 3) & 3); // V: 16 rows/gld

  auto stage_k = [&](int il, int buf) {
    const _Float16* src = Kp + (size_t)(wkv + il * 128) * 64;
    _Float16* dst = Kbase + (wave * 2 + buf) * 2048;
    #pragma unroll
    for (int j = 0; j < 4; j++)
      gld_lds16(src + (size_t)(j * 8 + krr) * 64 + kcb * 8,
                dst + (j * 64 + lane) * 8);
  };
  auto stage_v = [&](int il) {
    const _Float16* src = Vp + wkv + il * 128;
    #pragma unroll
    for (int j = 0; j < 4; j++)
      gld_lds16(src + (size_t)(j * 16 + (vrr & 15)) * N + vcb * 8,
                Vs + (j * 64 + lane) * 8);
  };

  // Prologue: Q (block-shared, 8KB), then K0, V0, K1 (per-wave private).
  #pragma unroll
  for (int i = 0; i < 2; i++) {
    int idx = tid + i * 256;
    int r = idx >> 3, cb = (idx ^ r) & 7;
    gld_lds16(Qp + (size_t)(q0 + r) * 64 + cb * 8, PQ + idx * 8);
  }
  stage_k(0, 0);
  stage_v(0);
  stage_k(1, 1);

  asm volatile("s_waitcnt vmcnt(12)" ::: "memory");   // own Q portion done
  __builtin_amdgcn_s_barrier();                       // Q resident (all waves)
  __builtin_amdgcn_sched_barrier(0);

  half8v qf[4][2];
  #pragma unroll
  for (int m = 0; m < 4; m++)
    #pragma unroll
    for (int ks = 0; ks < 2; ks++)
      qf[m][ks] = *(half8v*)&PQ[swz(m * 16 + l15, ks * 4 + qd)];

  asm volatile("s_waitcnt lgkmcnt(0)" ::: "memory");  // qf in regs
  __builtin_amdgcn_s_barrier();                       // before P overwrites Q
  __builtin_amdgcn_sched_barrier(0);

  floatx4 o[4][4] = {};
  float lsum[4] = {};

  #pragma unroll 2
  for (int i = 0; i < 16; ++i) {
    // top wait: K(i) resident (leaves V(i), K(i+1) in flight)
    if (i < 15) asm volatile("s_waitcnt vmcnt(8)" ::: "memory");
    else        asm volatile("s_waitcnt vmcnt(4)" ::: "memory");
    __builtin_amdgcn_sched_barrier(0);

    const _Float16* Kb = Kbase + (wave * 2 + (i & 1)) * 2048;

    // S^T = K·Q^T : s[nt][m], kv = nt*16+qd*4+r, q = m*16+l15 (within tile m)
    floatx4 s[2][4] = {};
    #pragma unroll
    for (int ks = 0; ks < 2; ks++) {
      half8v kf0 = *(half8v*)&Kb[swz(l15, ks * 4 + qd)];
      half8v kf1 = *(half8v*)&Kb[swz(16 + l15, ks * 4 + qd)];
      __builtin_amdgcn_s_setprio(1);
      #pragma unroll
      for (int m = 0; m < 4; m++) {
        s[0][m] = MFMA16(kf0, qf[m][ks], s[0][m]);
        s[1][m] = MFMA16(kf1, qf[m][ks], s[1][m]);
      }
      __builtin_amdgcn_s_setprio(0);
    }

    // p = 2^s; VALU lsum; pack -> private P slot (vswz, 64B rows).
    #pragma unroll
    for (int m = 0; m < 4; m++)
      #pragma unroll
      for (int nt = 0; nt < 2; nt++) {
        float p0 = __builtin_amdgcn_exp2f(s[nt][m][0]);
        float p1 = __builtin_amdgcn_exp2f(s[nt][m][1]);
        float p2 = __builtin_amdgcn_exp2f(s[nt][m][2]);
        float p3 = __builtin_amdgcn_exp2f(s[nt][m][3]);
        lsum[m] += (p0 + p1) + (p2 + p3);
        half2v h01 = pk16(p0, p1);
        half2v h23 = pk16(p2, p3);
        half4v pk;
        pk[0] = h01[0]; pk[1] = h01[1]; pk[2] = h23[0]; pk[3] = h23[1];
        *(half4v*)&Ps[vswz(m * 16 + l15, 2 * nt + (qd >> 1)) + (qd & 1) * 4] = pk;
      }

    // mid wait: V(i) resident (leaves K(i+1) in flight)
    if (i < 15) asm volatile("s_waitcnt vmcnt(4)" ::: "memory");
    else        asm volatile("s_waitcnt vmcnt(0)" ::: "memory");
    __builtin_amdgcn_sched_barrier(0);

    half8v pf[4], vfr[4];
    #pragma unroll
    for (int m = 0; m < 4; m++)
      pf[m] = *(half8v*)&Ps[vswz(m * 16 + l15, qd)];
    #pragma unroll
    for (int dt = 0; dt < 4; dt++)
      vfr[dt] = *(half8v*)&Vs[vswz(dt * 16 + l15, qd)];

    asm volatile("s_waitcnt lgkmcnt(0)" ::: "memory");  // reads done -> WAR-safe
    __builtin_amdgcn_sched_barrier(0);

    // prefetch: V(i+1) first, then K(i+2) (retirement-order matters)
    if (i <= 14) stage_v(i + 1);
    if (i <= 13) stage_k(i + 2, i & 1);
    __builtin_amdgcn_sched_barrier(0);

    // O += P·V
    __builtin_amdgcn_s_setprio(1);
    #pragma unroll
    for (int m = 0; m < 4; m++)
      #pragma unroll
      for (int dt = 0; dt < 4; dt++)
        o[m][dt] = MFMA16(pf[m], vfr[dt], o[m][dt]);
    __builtin_amdgcn_s_setprio(0);
  }

  // lsum: reduce across qd groups (q = m*16+l15 constant across qd).
  #pragma unroll
  for (int m = 0; m < 4; m++) {
    lsum[m] += __shfl_xor(lsum[m], 16);
    lsum[m] += __shfl_xor(lsum[m], 32);
  }

  // ---- epilogue: cross-wave reduction of O and lsum via (dead) LDS ----
  __syncthreads();
  float* sc    = (float*)smem;            // [4][64][64] f32 partials
  float* ls_sc = (float*)(smem + 65536);  // [4][64] f32 lsums
  float* myp = sc + wave * 4096;
  #pragma unroll
  for (int m = 0; m < 4; m++) {
    #pragma unroll
    for (int r = 0; r < 4; r++) {
      int row = m * 16 + qd * 4 + r;
      myp[row * 64 +  0 + l15] = o[m][0][r];
      myp[row * 64 + 16 + l15] = o[m][1][r];
      myp[row * 64 + 32 + l15] = o[m][2][r];
      myp[row * 64 + 48 + l15] = o[m][3][r];
    }
    if (qd == 0) ls_sc[wave * 64 + m * 16 + l15] = lsum[m];
  }
  __syncthreads();

  const int bb = bh >> 4, hh = bh & 15;
  #pragma unroll
  for (int j = 0; j < 4; j++) {
    int row = wave * 16 + j * 4 + qd;
    floatx4 a0 = *(floatx4*)&sc[(size_t)(0 * 64 + row) * 64 + l15 * 4];
    floatx4 a1 = *(floatx4*)&sc[(size_t)(1 * 64 + row) * 64 + l15 * 4];
    floatx4 a2 = *(floatx4*)&sc[(size_t)(2 * 64 + row) * 64 + l15 * 4];
    floatx4 a3 = *(floatx4*)&sc[(size_t)(3 * 64 + row) * 64 + l15 * 4];
    floatx4 sum = (a0 + a1) + (a2 + a3);
    float ls = ls_sc[row] + ls_sc[64 + row] + ls_sc[128 + row] + ls_sc[192 + row];
    float inv = 1.0f / ls;
    half2v h01 = pk16(sum[0] * inv, sum[1] * inv);
    half2v h23 = pk16(sum[2] * inv, sum[3] * inv);
    half4v hv;
    hv[0] = h01[0]; hv[1] = h01[1]; hv[2] = h23[0]; hv[3] = h23[1];
    *(half4v*)(aout + ((size_t)(bb * 2048 + q0 + row)) * 1024 + hh * 64 + l15 * 4) = hv;
  }
}

// ---------------------------------------------------------------------------
// Kernel 3: out projection — BK=64 (half the barriers, 2x MFMA per phase).
// Same 64x128 tile, 512 blocks (2/CU). Staging uses the 64-col swz pattern
// (identical to attn's Q staging); frag reads via swz.
// ---------------------------------------------------------------------------
__global__ __launch_bounds__(256) void out_gemm(
    const _Float16* __restrict__ A, const _Float16* __restrict__ WoT,
    const float* __restrict__ bo, float* __restrict__ Out)
{
  constexpr int K = 1024;
  __shared__ alignas(16) _Float16 As[64 * 64];    // 8 KB
  __shared__ alignas(16) _Float16 Bs[128 * 64];   // 16 KB

  const int m0 = blockIdx.x * 64;
  const int n0 = blockIdx.y * 128;
  const int tid = threadIdx.x;
  const int wave = tid >> 6, lane = tid & 63;
  const int qd = lane >> 4, l15 = lane & 15;
  const int wr = (wave >> 1) * 32, wc = (wave & 1) * 64;

  floatx4 acc[2][4] = {};

  for (int k0 = 0; k0 < K; k0 += 64) {
    #pragma unroll
    for (int i = 0; i < 2; i++) {
      int idx = tid + i * 256;
      int r = idx >> 3, cb = (idx ^ r) & 7;
      gld_lds16(A + (size_t)(m0 + r) * K + k0 + cb * 8, &As[idx * 8]);
    }
    #pragma unroll
    for (int i = 0; i < 4; i++) {
      int idx = tid + i * 256;
      int r = idx >> 3, cb = (idx ^ r) & 7;
      gld_lds16(WoT + (size_t)(n0 + r) * K + k0 + cb * 8, &Bs[idx * 8]);
    }
    __syncthreads();
    half8v a[2][2], b[4][2];
    #pragma unroll
    for (int it = 0; it < 2; it++)
      #pragma unroll
      for (int ks = 0; ks < 2; ks++)
        a[it][ks] = *(half8v*)&As[swz(wr + it * 16 + l15, ks * 4 + qd)];
    #pragma unroll
    for (int jt = 0; jt < 4; jt++)
      #pragma unroll
      for (int ks = 0; ks < 2; ks++)
        b[jt][ks] = *(half8v*)&Bs[swz(wc + jt * 16 + l15, ks * 4 + qd)];
    #pragma unroll
    for (int ks = 0; ks < 2; ks++)
      #pragma unroll
      for (int it = 0; it < 2; it++)
        #pragma unroll
        for (int jt = 0; jt < 4; jt++)
          acc[it][jt] = MFMA16(a[it][ks], b[jt][ks], acc[it][jt]);
    __syncthreads();
  }

  #pragma unroll
  for (int it = 0; it < 2; it++) {
    #pragma unroll
    for (int jt = 0; jt < 4; jt++) {
      int n = n0 + wc + jt * 16 + l15;
      float bias = bo[n];
      #pragma unroll
      for (int r = 0; r < 4; r++) {
        int m = m0 + wr + it * 16 + qd * 4 + r;
        Out[(size_t)m * 1024 + n] = acc[it][jt][r] + bias;
      }
    }
  }
}

// ---------------------------------------------------------------------------
extern "C" void kernel_launch(void* const* d_in, const int* in_sizes, int n_in,
                              void* d_out, int out_size, void* d_ws, size_t ws_size,
                              hipStream_t stream) {
  const float* X   = (const float*)d_in[0];
  const float* Wq  = (const float*)d_in[1];
  const float* Wkv = (const float*)d_in[2];
  const float* Wo  = (const float*)d_in[3];
  const float* bo  = (const float*)d_in[4];
  float* out = (float*)d_out;

  const size_t M4 = (size_t)4 * 1024 * 1024;
  _Float16* q_ws   = (_Float16*)d_ws;
  _Float16* k_ws   = q_ws + M4;
  _Float16* vT_ws  = k_ws + M4;
  _Float16* X16    = vT_ws + M4;
  _Float16* WqkvT  = X16 + M4;
  _Float16* WoT    = WqkvT + (size_t)3 * 1024 * 1024;
  _Float16* aout   = X16;  // X16 dead after qkv_gemm

  prep<<<3072, 256, 0, stream>>>(X, Wq, Wkv, Wo, X16, WqkvT, WoT);
  qkv_gemm<<<dim3(32, 24), 256, 0, stream>>>(X16, WqkvT, q_ws, k_ws, vT_ws);
  attn_kernel<<<1024, 256, 0, stream>>>(q_ws, k_ws, vT_ws, aout);
  out_gemm<<<dim3(64, 8), 256, 0, stream>>>(aout, WoT, bo, out);
}